// Round 4
// baseline (251.141 us; speedup 1.0000x reference)
//
#include <hip/hip_runtime.h>
#include <math.h>

// Problem constants
#define BATCH 8
#define NNODE 512
#define BN 4096           // BATCH*NNODE
#define DIM 128
#define HID 64
#define CAP 64            // max neighbors per row (mean ~20, 10 sigma margin)

__device__ __forceinline__ float sigmoidf(float x) {
  return 1.f / (1.f + expf(-x));
}
__device__ __forceinline__ float wave_sum(float v) {
  for (int off = 1; off < 64; off <<= 1) v += __shfl_xor(v, off, 64);
  return v;
}

// ---------------------------------------------------------------------------
// GIN block (R6-proven): 8 nodes/block (2/wave), gather via padded CSR with
// 8 independent row loads in flight.  W1 staged in LDS; W2 from global (L1).
// Accumulates block column sums into Ssum[batch*320 + SOFF + col].
// WRITEH=false skips the h-output store (h3 is dead: only its colsum is used).
// smem layout: W1s[CIN*64] | aggs[8*CIN] | zs[8*64]
// ---------------------------------------------------------------------------
template <int CIN, bool MASKED, int SOFF, bool WRITEH>
__device__ __forceinline__ void gin_block(
    float* smem, int node0, const float* hin, const float* W1g,
    const float* b1, const float* W2g, const float* b2, float eps1,
    const int* csr, const int* cnt, const float* mask, float* hout,
    float* Ssum) {
  float* W1s = smem;
  float* aggs = smem + CIN * HID;
  float* zs = aggs + 8 * CIN;
  int tid = threadIdx.x, wave = tid >> 6, lane = tid & 63;
  for (int t = tid; t < CIN * HID / 4; t += 256)
    ((float4*)W1s)[t] = ((const float4*)W1g)[t];
  for (int i = 0; i < 2; i++) {
    int ln = wave * 2 + i;
    int r = node0 + ln;
    int b9 = r & ~(NNODE - 1);
    const float* hi = hin + (size_t)r * CIN;
    float a0 = eps1 * hi[lane];
    float a1 = (CIN == 128) ? eps1 * hi[lane + 64] : 0.f;
    int n = cnt[r];
    const int* nb = csr + r * CAP;
    float mrow = MASKED ? mask[r] : 1.f;
    float s0 = 0.f, s1 = 0.f;
    for (int t = 0; t < n; t += 8) {  // CSR padded to CAP: safe over-read
      int4 ja = *(const int4*)&nb[t];
      int4 jb = *(const int4*)&nb[t + 4];
      int r0 = b9 + ja.x, r1 = b9 + ja.y, r2 = b9 + ja.z, r3 = b9 + ja.w;
      int r4 = b9 + jb.x, r5 = b9 + jb.y, r6 = b9 + jb.z, r7 = b9 + jb.w;
      float m0 = MASKED ? mask[r0] : 1.f;
      float m1 = (t + 1 < n) ? (MASKED ? mask[r1] : 1.f) : 0.f;
      float m2 = (t + 2 < n) ? (MASKED ? mask[r2] : 1.f) : 0.f;
      float m3 = (t + 3 < n) ? (MASKED ? mask[r3] : 1.f) : 0.f;
      float m4 = (t + 4 < n) ? (MASKED ? mask[r4] : 1.f) : 0.f;
      float m5 = (t + 5 < n) ? (MASKED ? mask[r5] : 1.f) : 0.f;
      float m6 = (t + 6 < n) ? (MASKED ? mask[r6] : 1.f) : 0.f;
      float m7 = (t + 7 < n) ? (MASKED ? mask[r7] : 1.f) : 0.f;
      const float* p0 = hin + (size_t)r0 * CIN;
      const float* p1 = hin + (size_t)r1 * CIN;
      const float* p2 = hin + (size_t)r2 * CIN;
      const float* p3 = hin + (size_t)r3 * CIN;
      const float* p4 = hin + (size_t)r4 * CIN;
      const float* p5 = hin + (size_t)r5 * CIN;
      const float* p6 = hin + (size_t)r6 * CIN;
      const float* p7 = hin + (size_t)r7 * CIN;
      s0 += m0 * p0[lane] + m1 * p1[lane] + m2 * p2[lane] + m3 * p3[lane] +
            m4 * p4[lane] + m5 * p5[lane] + m6 * p6[lane] + m7 * p7[lane];
      if (CIN == 128)
        s1 += m0 * p0[lane + 64] + m1 * p1[lane + 64] + m2 * p2[lane + 64] +
              m3 * p3[lane + 64] + m4 * p4[lane + 64] + m5 * p5[lane + 64] +
              m6 * p6[lane + 64] + m7 * p7[lane + 64];
    }
    a0 += mrow * s0;
    if (CIN == 128) a1 += mrow * s1;
    aggs[ln * CIN + lane] = a0;
    if (CIN == 128) aggs[ln * CIN + 64 + lane] = a1;
  }
  __syncthreads();  // W1s staged, aggs written
  const float* x0 = aggs + (wave * 2 + 0) * CIN;
  const float* x1 = aggs + (wave * 2 + 1) * CIN;
  float bb = b1[lane];
  float acc0 = bb, acc1 = bb;
  for (int k = 0; k < CIN; k += 4) {
    float w0 = W1s[(k + 0) * HID + lane];
    float w1 = W1s[(k + 1) * HID + lane];
    float w2 = W1s[(k + 2) * HID + lane];
    float w3 = W1s[(k + 3) * HID + lane];
    float4 a;
    a = *(const float4*)&x0[k];
    acc0 += a.x * w0 + a.y * w1 + a.z * w2 + a.w * w3;
    a = *(const float4*)&x1[k];
    acc1 += a.x * w0 + a.y * w1 + a.z * w2 + a.w * w3;
  }
  zs[(wave * 2 + 0) * HID + lane] = fmaxf(0.f, acc0);
  zs[(wave * 2 + 1) * HID + lane] = fmaxf(0.f, acc1);
  const float* z0 = zs + (wave * 2 + 0) * HID;
  const float* z1 = zs + (wave * 2 + 1) * HID;
  float b2b = b2[lane];
  float c0 = b2b, c1v = b2b;
  for (int k = 0; k < HID; k += 4) {
    float w0 = W2g[(k + 0) * HID + lane];   // global, coalesced, L1-resident
    float w1 = W2g[(k + 1) * HID + lane];
    float w2 = W2g[(k + 2) * HID + lane];
    float w3 = W2g[(k + 3) * HID + lane];
    float4 a;
    a = *(const float4*)&z0[k];
    c0 += a.x * w0 + a.y * w1 + a.z * w2 + a.w * w3;
    a = *(const float4*)&z1[k];
    c1v += a.x * w0 + a.y * w1 + a.z * w2 + a.w * w3;
  }
  float h0 = fmaxf(0.f, c0), h1v = fmaxf(0.f, c1v);
  if (WRITEH) {
    size_t rb = (size_t)(node0 + wave * 2) * HID + lane;
    hout[rb + 0 * HID] = h0;
    hout[rb + 1 * HID] = h1v;
  }
  // per-block column partial -> Ssum (zs rows of this wave are dead now)
  zs[(wave * 2) * HID + lane] = h0 + h1v;
  __syncthreads();
  if (tid < HID) {
    float tot = zs[0 * HID + tid] + zs[2 * HID + tid] + zs[4 * HID + tid] +
                zs[6 * HID + tid];
    atomicAdd(&Ssum[(node0 >> 9) * 320 + SOFF + tid], tot);
  }
}

// ---------------------------------------------------------------------------
// K1 (stage 1): blocks [0,1024): CSR build + degree (first: the 8MB A-scan
// is the only large cold-HBM read); [1024,1280): node MLPs (kappa + f0..f2),
// 64 nodes/block in 4 passes with W1 staged ONCE (amortizes the 32KB W1
// fetch 4x vs 16-node blocks and cuts block count 1024->256);
// [1280,1288): X column sums -> Ssum[b,0:128) via plain stores (sole
// writer); 1288: c1 + zero Ssum[:,128:320) + zero ticket.
// ---------------------------------------------------------------------------
__global__ __launch_bounds__(256) void k_stage1(
    const float* X, const float* A, const float* cW1, const float* cb1,
    const float* cW2, const float* cb2, const float* fW1, const float* fb1,
    const float* fW2, const float* fb2, const float* wm_W1, const float* wm_b1,
    const float* wm_W2, const float* wm_b2, const float* wm_W3,
    const float* wm_b3, float* kap, float* f, float* c1_out, int* csr,
    int* cnt_arr, float* deg, float* Ssum, int* ticket) {
  __shared__ float smem[10240];  // 40KB -> 4 blocks/CU
  int bid = blockIdx.x;
  int tid = threadIdx.x, wave = tid >> 6, lane = tid & 63;
  if (bid < 1024) {
    // ---- CSR build: 4 rows/block, 1 row/wave ----
    int r = bid * 4 + wave;
    const float* row = A + (size_t)r * NNODE;
    int base = r * CAP, cnt = 0;
    for (int c = 0; c < NNODE / 64; c++) {
      int j = c * 64 + lane;
      bool nz = (row[j] != 0.f);
      unsigned long long mb = __ballot(nz);
      if (nz) {
        int pos = __popcll(mb & ((1ull << lane) - 1ull));
        int slot = cnt + pos;
        if (slot < CAP) csr[base + slot] = j;
      }
      cnt += (int)__popcll(mb);
    }
    int cc = cnt < CAP ? cnt : CAP;
    if (lane >= cc) csr[base + lane] = 0;  // pad tail for int4 over-read
    if (lane == 0) {
      cnt_arr[r] = cc;
      deg[r] = (float)cnt;
    }
    return;
  }
  if (bid < 1280) {
    // ---- node MLPs: 64 nodes/block, 4 passes of 16 nodes ----
    int mb = bid - 1024;
    int m = mb >> 6;    // which MLP: 0=kappa, 1..3=f
    int grp = mb & 63;  // 64 groups of 64 nodes
    float* W1s = smem;          // 8192 floats
    float* xs = smem + 8192;    // 2048 floats (16 nodes)
    const float* W1 = (m == 0) ? cW1 : fW1 + (size_t)(m - 1) * DIM * HID;
    for (int t = tid; t < DIM * HID / 4; t += 256)
      ((float4*)W1s)[t] = ((const float4*)W1)[t];
    const float* b1 = (m == 0) ? cb1 : fb1 + (m - 1) * HID;
    const float* W2 = (m == 0) ? cW2 : fW2 + (m - 1) * HID;
    float b2v = (m == 0) ? cb2[0] : fb2[m - 1];
    float w2l = W2[lane];
    float bb = b1[lane];
    for (int p = 0; p < 4; p++) {
      int node0 = grp * 64 + p * 16;
      for (int t = tid; t < 16 * DIM / 4; t += 256)
        ((float4*)xs)[t] = ((const float4*)(X + (size_t)node0 * DIM))[t];
      __syncthreads();  // xs (and, on p=0, W1s) staged
      const float* x0 = xs + (wave * 4 + 0) * DIM;
      const float* x1 = xs + (wave * 4 + 1) * DIM;
      const float* x2 = xs + (wave * 4 + 2) * DIM;
      const float* x3 = xs + (wave * 4 + 3) * DIM;
      float acc0 = bb, acc1 = bb, acc2 = bb, acc3 = bb;
      for (int k = 0; k < DIM; k += 4) {
        float w0 = W1s[(k + 0) * HID + lane];
        float w1 = W1s[(k + 1) * HID + lane];
        float w2 = W1s[(k + 2) * HID + lane];
        float w3 = W1s[(k + 3) * HID + lane];
        float4 a;
        a = *(const float4*)&x0[k];
        acc0 += a.x * w0 + a.y * w1 + a.z * w2 + a.w * w3;
        a = *(const float4*)&x1[k];
        acc1 += a.x * w0 + a.y * w1 + a.z * w2 + a.w * w3;
        a = *(const float4*)&x2[k];
        acc2 += a.x * w0 + a.y * w1 + a.z * w2 + a.w * w3;
        a = *(const float4*)&x3[k];
        acc3 += a.x * w0 + a.y * w1 + a.z * w2 + a.w * w3;
      }
      float s0 = wave_sum(fmaxf(0.f, acc0) * w2l);
      float s1 = wave_sum(fmaxf(0.f, acc1) * w2l);
      float s2 = wave_sum(fmaxf(0.f, acc2) * w2l);
      float s3 = wave_sum(fmaxf(0.f, acc3) * w2l);
      if (lane < 4) {
        float sv = (lane == 0) ? s0 : (lane == 1) ? s1 : (lane == 2) ? s2 : s3;
        float s = sigmoidf(sv + b2v);
        int node = node0 + wave * 4 + lane;
        if (m == 0) kap[node] = s;
        else f[node * 3 + (m - 1)] = s;
      }
      if (p < 3) __syncthreads();  // xs consumed; safe to restage
    }
    return;
  }
  if (bid < 1288) {
    // ---- X column sums: one block per batch, sole writer of Ssum[b,0:128)
    int b = bid - 1280;
    int col = tid & 127, rg = tid >> 7;  // 2 row-groups of 256 rows
    const float* xb = X + (size_t)b * NNODE * DIM;
    float s = 0.f;
    for (int n = rg * 256; n < rg * 256 + 256; n++)
      s += xb[(size_t)n * DIM + col];
    smem[tid] = s;
    __syncthreads();
    if (tid < 128) Ssum[b * 320 + tid] = smem[tid] + smem[tid + 128];
    return;
  }
  // zero Ssum[:,128:320) + ticket (strictly precedes stage2-4 atomics,
  // stream order; Ssum[:,0:128) is fully written by the colsum blocks)
  for (int t = tid; t < BATCH * 192; t += 256)
    Ssum[(t / 192) * 320 + 128 + (t % 192)] = 0.f;
  if (tid == 0) *ticket = 0;
  // c1 = scalar weight-MLP(1.0)  (weights == c1*A since A is binary)
  float* u = smem;
  float* y = smem + 64;
  int l = tid;
  if (l < 64) u[l] = fmaxf(0.f, wm_W1[l] + wm_b1[l]);
  __syncthreads();
  if (l < 32) {
    float a = wm_b2[l];
    for (int k = 0; k < 64; k++) a += u[k] * wm_W2[k * 32 + l];
    y[l] = fmaxf(0.f, a);
  }
  __syncthreads();
  if (l == 0) {
    float a = wm_b3[0];
    for (int k = 0; k < 32; k++) a += y[k] * wm_W3[k];
    *c1_out = sigmoidf(a);
  }
}

// ---------------------------------------------------------------------------
// K2 (stage 2): [0,8): fused curvature pass1+pass2+loss, one block per
// batch, all per-node terms (gamma, df, f*df, s1) in LDS, one barrier
// between the two graph hops -> loss_part[b];
// [8,16): top-k rank masks; [16,528): GIN layer 0 (h1 colsums).
// ---------------------------------------------------------------------------
__global__ __launch_bounds__(256) void k_stage2(
    const float* X, const float* f, const float* kap, const int* p_ptr,
    const int* csr, const int* cnt, const float* deg, const float* c1p,
    const float* g0_W1, const float* g0_b1, const float* g0_W2,
    const float* g0_b2, const float* gin_eps, float* loss_part, float* M1,
    float* M2, float* h1, float* Ssum) {
  __shared__ float smem[9728];  // gin: 128*64+8*128+8*64; curv: 7680+4
  int bid = blockIdx.x;
  int tid = threadIdx.x;
  int wave = tid >> 6, lane = tid & 63;
  if (bid < BATCH) {
    // ---- fused curvature: batch b, 512 rows, 2 rows/thread ----
    int b = bid;
    float* fv = smem;            // 512*3
    float* ggv = smem + 1536;    // 512*9: [gamma,df,f*df] x3
    float* s1v = smem + 6144;    // 512*3
    float* part = smem + 7680;   // 4
    for (int t = tid; t < NNODE * 3; t += 256)
      fv[t] = f[b * NNODE * 3 + t];
    __syncthreads();
    float c1 = *c1p;
    // phase 1: per-row neighbor f sums -> gamma/df terms in LDS
    for (int rr = 0; rr < 2; rr++) {
      int r = tid * 2 + rr;
      int gr = b * NNODE + r;
      int n = cnt[gr];
      const int* nb = csr + gr * CAP;
      float s1[3] = {0, 0, 0}, s2[3] = {0, 0, 0};
      for (int t = 0; t < n; t += 4) {   // csr padded: safe over-read
        int4 j4 = *(const int4*)&nb[t];
        float w1 = (t + 1 < n) ? 1.f : 0.f;
        float w2 = (t + 2 < n) ? 1.f : 0.f;
        float w3 = (t + 3 < n) ? 1.f : 0.f;
        const float* p0 = &fv[j4.x * 3];
        const float* p1 = &fv[j4.y * 3];
        const float* p2 = &fv[j4.z * 3];
        const float* p3 = &fv[j4.w * 3];
        for (int i = 0; i < 3; i++) {
          float v0 = p0[i], v1 = p1[i], v2 = p2[i], v3 = p3[i];
          s1[i] += v0 + w1 * v1 + w2 * v2 + w3 * v3;
          s2[i] += v0 * v0 + w1 * v1 * v1 + w2 * v2 * v2 + w3 * v3 * v3;
        }
      }
      float dA = deg[gr];
      for (int i = 0; i < 3; i++) {
        float fi = fv[r * 3 + i];
        float gamma = 0.5f * c1 * (fi * fi * dA - 2.f * fi * s1[i] + s2[i]);
        float df = c1 * (fi * dA - s1[i]);
        ggv[r * 9 + i * 3 + 0] = gamma;
        ggv[r * 9 + i * 3 + 1] = df;
        ggv[r * 9 + i * 3 + 2] = fi * df;
        s1v[r * 3 + i] = s1[i];
      }
    }
    __syncthreads();
    // phase 2: neighbor sums of [gamma,df,f*df] -> loss
    float local = 0.f;
    for (int rr = 0; rr < 2; rr++) {
      int r = tid * 2 + rr;
      int gr = b * NNODE + r;
      int n = cnt[gr];
      const int* nb = csr + gr * CAP;
      float T[9];
      for (int c = 0; c < 9; c++) T[c] = 0.f;
      for (int t = 0; t < n; t += 4) {
        int4 j4 = *(const int4*)&nb[t];
        float w1 = (t + 1 < n) ? 1.f : 0.f;
        float w2 = (t + 2 < n) ? 1.f : 0.f;
        float w3 = (t + 3 < n) ? 1.f : 0.f;
        const float* g0 = &ggv[j4.x * 9];
        const float* g1 = &ggv[j4.y * 9];
        const float* g2 = &ggv[j4.z * 9];
        const float* g3 = &ggv[j4.w * 9];
        for (int c = 0; c < 9; c++)
          T[c] += g0[c] + w1 * g1[c] + w2 * g2[c] + w3 * g3[c];
      }
      float dA = deg[gr];
      float kp = kap[gr];
      for (int i = 0; i < 3; i++) {
        float fi = fv[r * 3 + i];
        float s1 = s1v[r * 3 + i];
        float gamma = ggv[r * 9 + i * 3 + 0];
        float df = ggv[r * 9 + i * 3 + 1];
        float dgamma = c1 * (gamma * dA - T[i * 3 + 0]);
        float gfd = 0.5f * c1 * (fi * df * dA - fi * T[i * 3 + 1] -
                                 df * s1 + T[i * 3 + 2]);
        float gamma2 = 0.5f * dgamma - gfd;
        local += fmaxf(0.f, kp * gamma - gamma2);
      }
      local -= 3.f * kp;   // "- kappa.sum()" once per f_i, per node
    }
    local = wave_sum(local);
    if (lane == 0) part[wave] = local;
    __syncthreads();
    if (tid == 0) loss_part[b] = part[0] + part[1] + part[2] + part[3];
    return;
  }
  if (bid < 2 * BATCH) {
    int b = bid - BATCH;
    float* ks = smem;
    for (int t = tid; t < NNODE; t += 256) ks[t] = kap[b * NNODE + t];
    __syncthreads();
    int p = *p_ptr;
    int num1 = (NNODE * p) / 100;
    int num2 = (NNODE * 2 * p) / 100;
    int numm = num1 > num2 ? num1 : num2;
    for (int i = tid; i < NNODE; i += 256) {
      float v = ks[i];
      int rank = 0;
      for (int j = 0; j < NNODE; j++) {
        float u = ks[j];
        rank += (u > v) || (u == v && j < i);  // jax.lax.top_k tie-break
      }
      M1[b * NNODE + i] = (rank < num1) ? 0.f : 1.f;
      M2[b * NNODE + i] = (rank < numm) ? 0.f : 1.f;
    }
    return;
  }
  gin_block<DIM, false, 128, true>(smem, (bid - 2 * BATCH) * 8, X, g0_W1,
                                   g0_b1, g0_W2, g0_b2, 1.f + gin_eps[0],
                                   csr, cnt, nullptr, h1, Ssum);
}

// ---------------------------------------------------------------------------
// K3 (stage 3): GIN layer 1 only (mask M1; h2 colsums -> Ssum[:,192:256]).
// ---------------------------------------------------------------------------
__global__ __launch_bounds__(256) void k_stage3(
    const float* h1, const float* g1_W1, const float* g1_b1,
    const float* g1_W2, const float* g1_b2, const float* gin_eps,
    const int* csr, const int* cnt, const float* M1, float* h2, float* Ssum) {
  __shared__ float smem[5120];  // 64*64+8*64+8*64
  gin_block<HID, true, 192, true>(smem, blockIdx.x * 8, h1, g1_W1, g1_b1,
                                  g1_W2, g1_b2, 1.f + gin_eps[1], csr, cnt,
                                  M1, h2, Ssum);
}

// ---------------------------------------------------------------------------
// K4 (stage 4): GIN layer 2 (mask M2 == M1*M2 by top-k nesting; h3 is DEAD
// -- only its colsum survives, accumulated into Ssum[:,256:320]) + folded
// readout: the LAST block (device ticket) computes out = Ssum @ out_W +
// out_b and the loss sum.
// Ordering (no fences needed): gin_block's trailing __syncthreads() lowers
// to per-wave s_waitcnt vmcnt(0) before s_barrier, so every block's
// device-scope Ssum atomicAdds are committed to the coherency point before
// tid0's ticket atomicAdd.  The last block reads Ssum with agent-scope
// atomic loads (atomics on both sides -> no reliance on L2 coherence).
// ---------------------------------------------------------------------------
__global__ __launch_bounds__(256) void k_stage4(
    const float* h2, const float* g2_W1, const float* g2_b1,
    const float* g2_W2, const float* g2_b2, const float* gin_eps,
    const int* csr, const int* cnt, const float* M2, float* Ssum,
    const float* out_W, const float* out_b, const float* loss_part,
    float* out, int* ticket) {
  __shared__ float smem[5120];
  __shared__ int lastf;
  gin_block<HID, true, 256, false>(smem, blockIdx.x * 8, h2, g2_W1, g2_b1,
                                   g2_W2, g2_b2, 1.f + gin_eps[2], csr, cnt,
                                   M2, nullptr, Ssum);
  __syncthreads();  // drains this block's Ssum atomicAdds (vmcnt(0)+barrier)
  if (threadIdx.x == 0)
    lastf = (atomicAdd(ticket, 1) == 511) ? 1 : 0;
  __syncthreads();
  if (lastf) {
    float* S = smem;  // 2560 floats, smem is dead now
    for (int i = threadIdx.x; i < BATCH * 320; i += 256)
      S[i] = __hip_atomic_load(&Ssum[i], __ATOMIC_RELAXED,
                               __HIP_MEMORY_SCOPE_AGENT);
    __syncthreads();
    int t = threadIdx.x;
    int b = t >> 5, o = t & 31;  // 8 batches x 10 outputs on threads 0..255
    if (o < 10) {
      float acc = out_b[o];
      const float* Sb = S + b * 320;
      for (int d = 0; d < 320; d++) acc += Sb[d] * out_W[d * 10 + o];
      out[b * 10 + o] = acc;
    }
    if (t == 0) {
      float ls = 0.f;
      for (int i = 0; i < BATCH; i++) ls += loss_part[i];
      out[80] = ls;
    }
  }
}

// ---------------------------------------------------------------------------
extern "C" void kernel_launch(void* const* d_in, const int* in_sizes, int n_in,
                              void* d_out, int out_size, void* d_ws,
                              size_t ws_size, hipStream_t stream) {
  const float* X       = (const float*)d_in[0];
  const float* A       = (const float*)d_in[1];
  const int*   p       = (const int*)d_in[2];
  const float* curv_W1 = (const float*)d_in[3];
  const float* curv_b1 = (const float*)d_in[4];
  const float* curv_W2 = (const float*)d_in[5];
  const float* curv_b2 = (const float*)d_in[6];
  const float* wm_W1   = (const float*)d_in[7];
  const float* wm_b1   = (const float*)d_in[8];
  const float* wm_W2   = (const float*)d_in[9];
  const float* wm_b2   = (const float*)d_in[10];
  const float* wm_W3   = (const float*)d_in[11];
  const float* wm_b3   = (const float*)d_in[12];
  const float* fn_W1   = (const float*)d_in[13];
  const float* fn_b1   = (const float*)d_in[14];
  const float* fn_W2   = (const float*)d_in[15];
  const float* fn_b2   = (const float*)d_in[16];
  const float* gin_eps = (const float*)d_in[17];
  const float* g0_W1   = (const float*)d_in[18];
  const float* g0_b1   = (const float*)d_in[19];
  const float* g0_W2   = (const float*)d_in[20];
  const float* g0_b2   = (const float*)d_in[21];
  const float* g1_W1   = (const float*)d_in[22];
  const float* g1_b1   = (const float*)d_in[23];
  const float* g1_W2   = (const float*)d_in[24];
  const float* g1_b2   = (const float*)d_in[25];
  const float* g2_W1   = (const float*)d_in[26];
  const float* g2_b1   = (const float*)d_in[27];
  const float* g2_W2   = (const float*)d_in[28];
  const float* g2_b2   = (const float*)d_in[29];
  const float* out_W   = (const float*)d_in[30];
  const float* out_b   = (const float*)d_in[31];
  float* out = (float*)d_out;

  float* ws = (float*)d_ws;
  size_t o = 0;
  float* loss_part = ws + o; o += 16;
  float* c1       = ws + o; o += 16;
  float* Ssum     = ws + o; o += BATCH * 320 + 16;
  float* kap      = ws + o; o += BN;
  float* f        = ws + o; o += (size_t)BN * 3 + 16;
  float* deg      = ws + o; o += BN;
  float* M1       = ws + o; o += BN;
  float* M2       = ws + o; o += BN;
  float* h1       = ws + o; o += (size_t)BN * HID;
  float* h2       = ws + o; o += (size_t)BN * HID;
  int* cnt  = (int*)(ws + o); o += BN;
  int* csr  = (int*)(ws + o); o += (size_t)BN * CAP;
  int* ticket = (int*)(ws + o); o += 16;

  k_stage1<<<1289, 256, 0, stream>>>(
      X, A, curv_W1, curv_b1, curv_W2, curv_b2, fn_W1, fn_b1, fn_W2, fn_b2,
      wm_W1, wm_b1, wm_W2, wm_b2, wm_W3, wm_b3, kap, f, c1, csr, cnt, deg,
      Ssum, ticket);
  k_stage2<<<2 * BATCH + 512, 256, 0, stream>>>(
      X, f, kap, p, csr, cnt, deg, c1, g0_W1, g0_b1, g0_W2, g0_b2, gin_eps,
      loss_part, M1, M2, h1, Ssum);
  k_stage3<<<512, 256, 0, stream>>>(h1, g1_W1, g1_b1, g1_W2, g1_b2, gin_eps,
                                    csr, cnt, M1, h2, Ssum);
  k_stage4<<<512, 256, 0, stream>>>(h2, g2_W1, g2_b1, g2_W2, g2_b2, gin_eps,
                                    csr, cnt, M2, Ssum, out_W, out_b,
                                    loss_part, out, ticket);
}

// Round 5
// 195.229 us; speedup vs baseline: 1.2864x; 1.2864x over previous
//
#include <hip/hip_runtime.h>
#include <math.h>

// Problem constants
#define BATCH 8
#define NNODE 512
#define BN 4096           // BATCH*NNODE
#define DIM 128
#define HID 64
#define CAP 64            // max neighbors per row (mean ~20, 10 sigma margin)

__device__ __forceinline__ float sigmoidf(float x) {
  return 1.f / (1.f + expf(-x));
}
__device__ __forceinline__ float wave_sum(float v) {
  for (int off = 1; off < 64; off <<= 1) v += __shfl_xor(v, off, 64);
  return v;
}

// ---------------------------------------------------------------------------
// GIN block (R6-proven): 8 nodes/block (2/wave), gather via padded CSR with
// 8 independent row loads in flight.  W1 staged in LDS; W2 from global (L1).
// Accumulates block column sums into Ssum[batch*320 + SOFF + col].
// WRITEH=false skips the h-output store (h3 is dead: only its colsum is used).
// smem layout: W1s[CIN*64] | aggs[8*CIN] | zs[8*64]
// ---------------------------------------------------------------------------
template <int CIN, bool MASKED, int SOFF, bool WRITEH>
__device__ __forceinline__ void gin_block(
    float* smem, int node0, const float* hin, const float* W1g,
    const float* b1, const float* W2g, const float* b2, float eps1,
    const int* csr, const int* cnt, const float* mask, float* hout,
    float* Ssum) {
  float* W1s = smem;
  float* aggs = smem + CIN * HID;
  float* zs = aggs + 8 * CIN;
  int tid = threadIdx.x, wave = tid >> 6, lane = tid & 63;
  for (int t = tid; t < CIN * HID / 4; t += 256)
    ((float4*)W1s)[t] = ((const float4*)W1g)[t];
  for (int i = 0; i < 2; i++) {
    int ln = wave * 2 + i;
    int r = node0 + ln;
    int b9 = r & ~(NNODE - 1);
    const float* hi = hin + (size_t)r * CIN;
    float a0 = eps1 * hi[lane];
    float a1 = (CIN == 128) ? eps1 * hi[lane + 64] : 0.f;
    int n = cnt[r];
    const int* nb = csr + r * CAP;
    float mrow = MASKED ? mask[r] : 1.f;
    float s0 = 0.f, s1 = 0.f;
    for (int t = 0; t < n; t += 8) {  // CSR padded to CAP: safe over-read
      int4 ja = *(const int4*)&nb[t];
      int4 jb = *(const int4*)&nb[t + 4];
      int r0 = b9 + ja.x, r1 = b9 + ja.y, r2 = b9 + ja.z, r3 = b9 + ja.w;
      int r4 = b9 + jb.x, r5 = b9 + jb.y, r6 = b9 + jb.z, r7 = b9 + jb.w;
      float m0 = MASKED ? mask[r0] : 1.f;
      float m1 = (t + 1 < n) ? (MASKED ? mask[r1] : 1.f) : 0.f;
      float m2 = (t + 2 < n) ? (MASKED ? mask[r2] : 1.f) : 0.f;
      float m3 = (t + 3 < n) ? (MASKED ? mask[r3] : 1.f) : 0.f;
      float m4 = (t + 4 < n) ? (MASKED ? mask[r4] : 1.f) : 0.f;
      float m5 = (t + 5 < n) ? (MASKED ? mask[r5] : 1.f) : 0.f;
      float m6 = (t + 6 < n) ? (MASKED ? mask[r6] : 1.f) : 0.f;
      float m7 = (t + 7 < n) ? (MASKED ? mask[r7] : 1.f) : 0.f;
      const float* p0 = hin + (size_t)r0 * CIN;
      const float* p1 = hin + (size_t)r1 * CIN;
      const float* p2 = hin + (size_t)r2 * CIN;
      const float* p3 = hin + (size_t)r3 * CIN;
      const float* p4 = hin + (size_t)r4 * CIN;
      const float* p5 = hin + (size_t)r5 * CIN;
      const float* p6 = hin + (size_t)r6 * CIN;
      const float* p7 = hin + (size_t)r7 * CIN;
      s0 += m0 * p0[lane] + m1 * p1[lane] + m2 * p2[lane] + m3 * p3[lane] +
            m4 * p4[lane] + m5 * p5[lane] + m6 * p6[lane] + m7 * p7[lane];
      if (CIN == 128)
        s1 += m0 * p0[lane + 64] + m1 * p1[lane + 64] + m2 * p2[lane + 64] +
              m3 * p3[lane + 64] + m4 * p4[lane + 64] + m5 * p5[lane + 64] +
              m6 * p6[lane + 64] + m7 * p7[lane + 64];
    }
    a0 += mrow * s0;
    if (CIN == 128) a1 += mrow * s1;
    aggs[ln * CIN + lane] = a0;
    if (CIN == 128) aggs[ln * CIN + 64 + lane] = a1;
  }
  __syncthreads();  // W1s staged, aggs written
  const float* x0 = aggs + (wave * 2 + 0) * CIN;
  const float* x1 = aggs + (wave * 2 + 1) * CIN;
  float bb = b1[lane];
  float acc0 = bb, acc1 = bb;
  for (int k = 0; k < CIN; k += 4) {
    float w0 = W1s[(k + 0) * HID + lane];
    float w1 = W1s[(k + 1) * HID + lane];
    float w2 = W1s[(k + 2) * HID + lane];
    float w3 = W1s[(k + 3) * HID + lane];
    float4 a;
    a = *(const float4*)&x0[k];
    acc0 += a.x * w0 + a.y * w1 + a.z * w2 + a.w * w3;
    a = *(const float4*)&x1[k];
    acc1 += a.x * w0 + a.y * w1 + a.z * w2 + a.w * w3;
  }
  zs[(wave * 2 + 0) * HID + lane] = fmaxf(0.f, acc0);
  zs[(wave * 2 + 1) * HID + lane] = fmaxf(0.f, acc1);
  const float* z0 = zs + (wave * 2 + 0) * HID;
  const float* z1 = zs + (wave * 2 + 1) * HID;
  float b2b = b2[lane];
  float c0 = b2b, c1v = b2b;
  for (int k = 0; k < HID; k += 4) {
    float w0 = W2g[(k + 0) * HID + lane];   // global, coalesced, L1-resident
    float w1 = W2g[(k + 1) * HID + lane];
    float w2 = W2g[(k + 2) * HID + lane];
    float w3 = W2g[(k + 3) * HID + lane];
    float4 a;
    a = *(const float4*)&z0[k];
    c0 += a.x * w0 + a.y * w1 + a.z * w2 + a.w * w3;
    a = *(const float4*)&z1[k];
    c1v += a.x * w0 + a.y * w1 + a.z * w2 + a.w * w3;
  }
  float h0 = fmaxf(0.f, c0), h1v = fmaxf(0.f, c1v);
  if (WRITEH) {
    size_t rb = (size_t)(node0 + wave * 2) * HID + lane;
    hout[rb + 0 * HID] = h0;
    hout[rb + 1 * HID] = h1v;
  }
  // per-block column partial -> Ssum (zs rows of this wave are dead now)
  zs[(wave * 2) * HID + lane] = h0 + h1v;
  __syncthreads();
  if (tid < HID) {
    float tot = zs[0 * HID + tid] + zs[2 * HID + tid] + zs[4 * HID + tid] +
                zs[6 * HID + tid];
    atomicAdd(&Ssum[(node0 >> 9) * 320 + SOFF + tid], tot);
  }
}

// ---------------------------------------------------------------------------
// K1 (stage 1): blocks [0,1024): node MLPs (kappa + f0..f2), 16 nodes/block,
// W1 in LDS (many SHORT blocks: load balance beats W1-staging amortization
// for this latency-bound kernel -- R4's 64-node blocks serialized the tail);
// [1024,2048): CSR build + degree; 2048: c1 + zero Ssum.
// ---------------------------------------------------------------------------
__global__ __launch_bounds__(256) void k_stage1(
    const float* X, const float* A, const float* cW1, const float* cb1,
    const float* cW2, const float* cb2, const float* fW1, const float* fb1,
    const float* fW2, const float* fb2, const float* wm_W1, const float* wm_b1,
    const float* wm_W2, const float* wm_b2, const float* wm_W3,
    const float* wm_b3, float* kap, float* f, float* c1_out, int* csr,
    int* cnt_arr, float* deg, float* Ssum) {
  __shared__ float smem[10240];  // 40KB
  int bid = blockIdx.x;
  int tid = threadIdx.x, wave = tid >> 6, lane = tid & 63;
  if (bid < 1024) {
    int m = bid >> 8;   // which MLP: 0=kappa, 1..3=f
    int grp = bid & 255;
    float* W1s = smem;          // 8192 floats
    float* xs = smem + 8192;    // 2048 floats
    int node0 = grp * 16;
    const float* W1 = (m == 0) ? cW1 : fW1 + (size_t)(m - 1) * DIM * HID;
    for (int t = tid; t < 16 * DIM / 4; t += 256)
      ((float4*)xs)[t] = ((const float4*)(X + (size_t)node0 * DIM))[t];
    for (int t = tid; t < DIM * HID / 4; t += 256)
      ((float4*)W1s)[t] = ((const float4*)W1)[t];
    __syncthreads();
    const float* b1 = (m == 0) ? cb1 : fb1 + (m - 1) * HID;
    const float* W2 = (m == 0) ? cW2 : fW2 + (m - 1) * HID;
    float b2v = (m == 0) ? cb2[0] : fb2[m - 1];
    const float* x0 = xs + (wave * 4 + 0) * DIM;
    const float* x1 = xs + (wave * 4 + 1) * DIM;
    const float* x2 = xs + (wave * 4 + 2) * DIM;
    const float* x3 = xs + (wave * 4 + 3) * DIM;
    float w2l = W2[lane];
    float bb = b1[lane];
    float acc0 = bb, acc1 = bb, acc2 = bb, acc3 = bb;
    for (int k = 0; k < DIM; k += 4) {
      float w0 = W1s[(k + 0) * HID + lane];
      float w1 = W1s[(k + 1) * HID + lane];
      float w2 = W1s[(k + 2) * HID + lane];
      float w3 = W1s[(k + 3) * HID + lane];
      float4 a;
      a = *(const float4*)&x0[k];
      acc0 += a.x * w0 + a.y * w1 + a.z * w2 + a.w * w3;
      a = *(const float4*)&x1[k];
      acc1 += a.x * w0 + a.y * w1 + a.z * w2 + a.w * w3;
      a = *(const float4*)&x2[k];
      acc2 += a.x * w0 + a.y * w1 + a.z * w2 + a.w * w3;
      a = *(const float4*)&x3[k];
      acc3 += a.x * w0 + a.y * w1 + a.z * w2 + a.w * w3;
    }
    float s0 = wave_sum(fmaxf(0.f, acc0) * w2l);
    float s1 = wave_sum(fmaxf(0.f, acc1) * w2l);
    float s2 = wave_sum(fmaxf(0.f, acc2) * w2l);
    float s3 = wave_sum(fmaxf(0.f, acc3) * w2l);
    if (lane < 4) {
      float sv = (lane == 0) ? s0 : (lane == 1) ? s1 : (lane == 2) ? s2 : s3;
      float s = sigmoidf(sv + b2v);
      int node = node0 + wave * 4 + lane;
      if (m == 0) kap[node] = s;
      else f[node * 3 + (m - 1)] = s;
    }
    return;
  }
  if (bid < 2048) {
    int r = (bid - 1024) * 4 + wave;
    const float* row = A + (size_t)r * NNODE;
    int base = r * CAP, cnt = 0;
    for (int c = 0; c < NNODE / 64; c++) {
      int j = c * 64 + lane;
      bool nz = (row[j] != 0.f);
      unsigned long long mb = __ballot(nz);
      if (nz) {
        int pos = __popcll(mb & ((1ull << lane) - 1ull));
        int slot = cnt + pos;
        if (slot < CAP) csr[base + slot] = j;
      }
      cnt += (int)__popcll(mb);
    }
    int cc = cnt < CAP ? cnt : CAP;
    if (lane >= cc) csr[base + lane] = 0;  // pad tail for int4 over-read
    if (lane == 0) {
      cnt_arr[r] = cc;
      deg[r] = (float)cnt;
    }
    return;
  }
  // zero Ssum (strictly precedes all stage2-4 atomics, stream order)
  for (int t = tid; t < BATCH * 320; t += 256) Ssum[t] = 0.f;
  // c1 = scalar weight-MLP(1.0)  (weights == c1*A since A is binary)
  float* u = smem;
  float* y = smem + 64;
  int l = tid;
  if (l < 64) u[l] = fmaxf(0.f, wm_W1[l] + wm_b1[l]);
  __syncthreads();
  if (l < 32) {
    float a = wm_b2[l];
    for (int k = 0; k < 64; k++) a += u[k] * wm_W2[k * 32 + l];
    y[l] = fmaxf(0.f, a);
  }
  __syncthreads();
  if (l == 0) {
    float a = wm_b3[0];
    for (int k = 0; k < 32; k++) a += y[k] * wm_W3[k];
    *c1_out = sigmoidf(a);
  }
}

// ---------------------------------------------------------------------------
// K2 (stage 2): [0,8): fused curvature pass1+pass2+loss, one block per
// batch, all per-node terms (gamma, df, f*df, s1) in LDS, one barrier
// between the two graph hops -> loss_part[b];
// [8,16): top-k rank masks; [16,528): GIN layer 0 (h1 colsums);
// [528,592): X column sums -> Ssum[:,0:128] via atomicAdd.
// ---------------------------------------------------------------------------
__global__ __launch_bounds__(256) void k_stage2(
    const float* X, const float* f, const float* kap, const int* p_ptr,
    const int* csr, const int* cnt, const float* deg, const float* c1p,
    const float* g0_W1, const float* g0_b1, const float* g0_W2,
    const float* g0_b2, const float* gin_eps, float* loss_part, float* M1,
    float* M2, float* h1, float* Ssum) {
  __shared__ float smem[9728];  // gin: 128*64+8*128+8*64; curv: 7680+4
  int bid = blockIdx.x;
  int tid = threadIdx.x;
  int wave = tid >> 6, lane = tid & 63;
  if (bid < BATCH) {
    // ---- fused curvature: batch b, 512 rows, 2 rows/thread ----
    int b = bid;
    float* fv = smem;            // 512*3
    float* ggv = smem + 1536;    // 512*9: [gamma,df,f*df] x3
    float* s1v = smem + 6144;    // 512*3
    float* part = smem + 7680;   // 4
    for (int t = tid; t < NNODE * 3; t += 256)
      fv[t] = f[b * NNODE * 3 + t];
    __syncthreads();
    float c1 = *c1p;
    // phase 1: per-row neighbor f sums -> gamma/df terms in LDS
    for (int rr = 0; rr < 2; rr++) {
      int r = tid * 2 + rr;
      int gr = b * NNODE + r;
      int n = cnt[gr];
      const int* nb = csr + gr * CAP;
      float s1[3] = {0, 0, 0}, s2[3] = {0, 0, 0};
      for (int t = 0; t < n; t += 4) {   // csr padded: safe over-read
        int4 j4 = *(const int4*)&nb[t];
        float w1 = (t + 1 < n) ? 1.f : 0.f;
        float w2 = (t + 2 < n) ? 1.f : 0.f;
        float w3 = (t + 3 < n) ? 1.f : 0.f;
        const float* p0 = &fv[j4.x * 3];
        const float* p1 = &fv[j4.y * 3];
        const float* p2 = &fv[j4.z * 3];
        const float* p3 = &fv[j4.w * 3];
        for (int i = 0; i < 3; i++) {
          float v0 = p0[i], v1 = p1[i], v2 = p2[i], v3 = p3[i];
          s1[i] += v0 + w1 * v1 + w2 * v2 + w3 * v3;
          s2[i] += v0 * v0 + w1 * v1 * v1 + w2 * v2 * v2 + w3 * v3 * v3;
        }
      }
      float dA = deg[gr];
      for (int i = 0; i < 3; i++) {
        float fi = fv[r * 3 + i];
        float gamma = 0.5f * c1 * (fi * fi * dA - 2.f * fi * s1[i] + s2[i]);
        float df = c1 * (fi * dA - s1[i]);
        ggv[r * 9 + i * 3 + 0] = gamma;
        ggv[r * 9 + i * 3 + 1] = df;
        ggv[r * 9 + i * 3 + 2] = fi * df;
        s1v[r * 3 + i] = s1[i];
      }
    }
    __syncthreads();
    // phase 2: neighbor sums of [gamma,df,f*df] -> loss
    float local = 0.f;
    for (int rr = 0; rr < 2; rr++) {
      int r = tid * 2 + rr;
      int gr = b * NNODE + r;
      int n = cnt[gr];
      const int* nb = csr + gr * CAP;
      float T[9];
      for (int c = 0; c < 9; c++) T[c] = 0.f;
      for (int t = 0; t < n; t += 4) {
        int4 j4 = *(const int4*)&nb[t];
        float w1 = (t + 1 < n) ? 1.f : 0.f;
        float w2 = (t + 2 < n) ? 1.f : 0.f;
        float w3 = (t + 3 < n) ? 1.f : 0.f;
        const float* g0 = &ggv[j4.x * 9];
        const float* g1 = &ggv[j4.y * 9];
        const float* g2 = &ggv[j4.z * 9];
        const float* g3 = &ggv[j4.w * 9];
        for (int c = 0; c < 9; c++)
          T[c] += g0[c] + w1 * g1[c] + w2 * g2[c] + w3 * g3[c];
      }
      float dA = deg[gr];
      float kp = kap[gr];
      for (int i = 0; i < 3; i++) {
        float fi = fv[r * 3 + i];
        float s1 = s1v[r * 3 + i];
        float gamma = ggv[r * 9 + i * 3 + 0];
        float df = ggv[r * 9 + i * 3 + 1];
        float dgamma = c1 * (gamma * dA - T[i * 3 + 0]);
        float gfd = 0.5f * c1 * (fi * df * dA - fi * T[i * 3 + 1] -
                                 df * s1 + T[i * 3 + 2]);
        float gamma2 = 0.5f * dgamma - gfd;
        local += fmaxf(0.f, kp * gamma - gamma2);
      }
      local -= 3.f * kp;   // "- kappa.sum()" once per f_i, per node
    }
    local = wave_sum(local);
    if (lane == 0) part[wave] = local;
    __syncthreads();
    if (tid == 0) loss_part[b] = part[0] + part[1] + part[2] + part[3];
    return;
  }
  if (bid < 2 * BATCH) {
    int b = bid - BATCH;
    float* ks = smem;
    for (int t = tid; t < NNODE; t += 256) ks[t] = kap[b * NNODE + t];
    __syncthreads();
    int p = *p_ptr;
    int num1 = (NNODE * p) / 100;
    int num2 = (NNODE * 2 * p) / 100;
    int numm = num1 > num2 ? num1 : num2;
    for (int i = tid; i < NNODE; i += 256) {
      float v = ks[i];
      int rank = 0;
      for (int j = 0; j < NNODE; j++) {
        float u = ks[j];
        rank += (u > v) || (u == v && j < i);  // jax.lax.top_k tie-break
      }
      M1[b * NNODE + i] = (rank < num1) ? 0.f : 1.f;
      M2[b * NNODE + i] = (rank < numm) ? 0.f : 1.f;
    }
    return;
  }
  if (bid < 2 * BATCH + 512) {
    gin_block<DIM, false, 128, true>(smem, (bid - 2 * BATCH) * 8, X, g0_W1,
                                     g0_b1, g0_W2, g0_b2, 1.f + gin_eps[0],
                                     csr, cnt, nullptr, h1, Ssum);
    return;
  }
  // X column sums: 64 blocks, each a batch-slice of 64 rows x 128 cols
  int idx = bid - (2 * BATCH + 512);
  int b = idx >> 3, sl = idx & 7;
  int col = tid & 127, rg = tid >> 7;  // 2 row-groups
  const float* xb = X + (size_t)b * NNODE * DIM;
  int n0 = sl * 64;
  float s = 0.f;
  for (int n = n0 + rg; n < n0 + 64; n += 2) s += xb[(size_t)n * DIM + col];
  smem[tid] = s;
  __syncthreads();
  if (tid < 128)
    atomicAdd(&Ssum[b * 320 + col], smem[tid] + smem[tid + 128]);
}

// ---------------------------------------------------------------------------
// K3 (stage 3): GIN layer 1 only (mask M1; h2 colsums -> Ssum[:,192:256]).
// ---------------------------------------------------------------------------
__global__ __launch_bounds__(256) void k_stage3(
    const float* h1, const float* g1_W1, const float* g1_b1,
    const float* g1_W2, const float* g1_b2, const float* gin_eps,
    const int* csr, const int* cnt, const float* M1, float* h2, float* Ssum) {
  __shared__ float smem[5120];  // 64*64+8*64+8*64
  gin_block<HID, true, 192, true>(smem, blockIdx.x * 8, h1, g1_W1, g1_b1,
                                  g1_W2, g1_b2, 1.f + gin_eps[1], csr, cnt,
                                  M1, h2, Ssum);
}

// ---------------------------------------------------------------------------
// K4 (stage 4): GIN layer 2 (mask M2 == M1*M2 by top-k nesting).  h3 is
// DEAD even in the baseline: only its column sum survives, and gin_block
// accumulates that into Ssum[:,256:320] directly -> WRITEH=false deletes
// 1MB of stores for free.
// ---------------------------------------------------------------------------
__global__ __launch_bounds__(256) void k_stage4(
    const float* h2, const float* g2_W1, const float* g2_b1,
    const float* g2_W2, const float* g2_b2, const float* gin_eps,
    const int* csr, const int* cnt, const float* M2, float* Ssum) {
  __shared__ float smem[5120];
  gin_block<HID, true, 256, false>(smem, blockIdx.x * 8, h2, g2_W1, g2_b1,
                                   g2_W2, g2_b2, 1.f + gin_eps[2], csr, cnt,
                                   M2, nullptr, Ssum);
}

// ---------------------------------------------------------------------------
// K5: tiny readout: out[b] = Ssum[b] @ out_W + out_b; loss from 8 partials.
// ---------------------------------------------------------------------------
__global__ __launch_bounds__(320) void k_out(
    const float* Ssum, const float* out_W, const float* out_b,
    const float* loss_part, float* out) {
  int b = blockIdx.x;
  int t = threadIdx.x;  // 320
  __shared__ float S[320];
  S[t] = Ssum[b * 320 + t];
  __syncthreads();
  if (t < 10) {
    float acc = out_b[t];
    for (int d = 0; d < 320; d++) acc += S[d] * out_W[d * 10 + t];
    out[b * 10 + t] = acc;
  }
  if (b == 0 && t == 0) {
    float ls = 0.f;
    for (int i = 0; i < BATCH; i++) ls += loss_part[i];
    out[80] = ls;
  }
}

// ---------------------------------------------------------------------------
extern "C" void kernel_launch(void* const* d_in, const int* in_sizes, int n_in,
                              void* d_out, int out_size, void* d_ws,
                              size_t ws_size, hipStream_t stream) {
  const float* X       = (const float*)d_in[0];
  const float* A       = (const float*)d_in[1];
  const int*   p       = (const int*)d_in[2];
  const float* curv_W1 = (const float*)d_in[3];
  const float* curv_b1 = (const float*)d_in[4];
  const float* curv_W2 = (const float*)d_in[5];
  const float* curv_b2 = (const float*)d_in[6];
  const float* wm_W1   = (const float*)d_in[7];
  const float* wm_b1   = (const float*)d_in[8];
  const float* wm_W2   = (const float*)d_in[9];
  const float* wm_b2   = (const float*)d_in[10];
  const float* wm_W3   = (const float*)d_in[11];
  const float* wm_b3   = (const float*)d_in[12];
  const float* fn_W1   = (const float*)d_in[13];
  const float* fn_b1   = (const float*)d_in[14];
  const float* fn_W2   = (const float*)d_in[15];
  const float* fn_b2   = (const float*)d_in[16];
  const float* gin_eps = (const float*)d_in[17];
  const float* g0_W1   = (const float*)d_in[18];
  const float* g0_b1   = (const float*)d_in[19];
  const float* g0_W2   = (const float*)d_in[20];
  const float* g0_b2   = (const float*)d_in[21];
  const float* g1_W1   = (const float*)d_in[22];
  const float* g1_b1   = (const float*)d_in[23];
  const float* g1_W2   = (const float*)d_in[24];
  const float* g1_b2   = (const float*)d_in[25];
  const float* g2_W1   = (const float*)d_in[26];
  const float* g2_b1   = (const float*)d_in[27];
  const float* g2_W2   = (const float*)d_in[28];
  const float* g2_b2   = (const float*)d_in[29];
  const float* out_W   = (const float*)d_in[30];
  const float* out_b   = (const float*)d_in[31];
  float* out = (float*)d_out;

  float* ws = (float*)d_ws;
  size_t o = 0;
  float* loss_part = ws + o; o += 16;
  float* c1       = ws + o; o += 16;
  float* Ssum     = ws + o; o += BATCH * 320 + 16;
  float* kap      = ws + o; o += BN;
  float* f        = ws + o; o += (size_t)BN * 3 + 16;
  float* deg      = ws + o; o += BN;
  float* M1       = ws + o; o += BN;
  float* M2       = ws + o; o += BN;
  float* h1       = ws + o; o += (size_t)BN * HID;
  float* h2       = ws + o; o += (size_t)BN * HID;
  int* cnt  = (int*)(ws + o); o += BN;
  int* csr  = (int*)(ws + o); o += (size_t)BN * CAP;

  k_stage1<<<2049, 256, 0, stream>>>(
      X, A, curv_W1, curv_b1, curv_W2, curv_b2, fn_W1, fn_b1, fn_W2, fn_b2,
      wm_W1, wm_b1, wm_W2, wm_b2, wm_W3, wm_b3, kap, f, c1, csr, cnt, deg,
      Ssum);
  k_stage2<<<2 * BATCH + 512 + 64, 256, 0, stream>>>(
      X, f, kap, p, csr, cnt, deg, c1, g0_W1, g0_b1, g0_W2, g0_b2, gin_eps,
      loss_part, M1, M2, h1, Ssum);
  k_stage3<<<512, 256, 0, stream>>>(h1, g1_W1, g1_b1, g1_W2, g1_b2, gin_eps,
                                    csr, cnt, M1, h2, Ssum);
  k_stage4<<<512, 256, 0, stream>>>(h2, g2_W1, g2_b1, g2_W2, g2_b2, gin_eps,
                                    csr, cnt, M2, Ssum);
  k_out<<<BATCH, 320, 0, stream>>>(Ssum, out_W, out_b, loss_part, out);
}